// Round 6
// baseline (311.382 us; speedup 1.0000x reference)
//
#include <hip/hip_runtime.h>
#include <hip/hip_fp16.h>

#define POOL 7
#define NBIN 49
#define SP_SCALE 0.25f

constexpr int Cc = 256, Hc = 200, Wc = 336;
constexpr int HWc = Hc * Wc;          // 67200

// ---------------- Kernel 1: NCHW fp32 -> NHWC fp16 transpose ----------------
// block (8,32): tx 0..7 (4 floats each), ty 0..31
__global__ __launch_bounds__(256) void transpose_f16_kernel(
    const float* __restrict__ in, __half* __restrict__ outp) {
  __shared__ float tile[32][33];
  int b  = blockIdx.z;
  int p0 = blockIdx.x * 32;   // spatial
  int c0 = blockIdx.y * 32;   // channel
  const float* src = in   + (size_t)b * Cc * HWc;
  __half*      dst = outp + (size_t)b * Cc * HWc;
  int tx = threadIdx.x;   // 0..7
  int ty = threadIdx.y;   // 0..31

  float4 v = *(const float4*)(src + (size_t)(c0 + ty) * HWc + p0 + tx * 4);
  tile[ty][tx * 4 + 0] = v.x;
  tile[ty][tx * 4 + 1] = v.y;
  tile[ty][tx * 4 + 2] = v.z;
  tile[ty][tx * 4 + 3] = v.w;
  __syncthreads();
  union { __half h[4]; uint2 u; } o;
  o.h[0] = __float2half(tile[tx * 4 + 0][ty]);
  o.h[1] = __float2half(tile[tx * 4 + 1][ty]);
  o.h[2] = __float2half(tile[tx * 4 + 2][ty]);
  o.h[3] = __float2half(tile[tx * 4 + 3][ty]);
  *(uint2*)(dst + (size_t)(p0 + ty) * Cc + c0 + tx * 4) = o.u;
}

// ---------------- Kernel 2: gather. 8 bins/block, thread = 8 channels (16B loads) ----
// Separable 4x4 corner grid: rows[4] x cols[4], weight = wy[r]*wx[c].
__global__ __launch_bounds__(256) void gather_kernel(
    const __half* __restrict__ ft, const float* __restrict__ rois,
    float* __restrict__ out, int N) {
  int T  = N * NBIN;
  int nb = (T + 7) >> 3;                // 8 bins per 256-thread block
  // XCD-bijective swizzle: same-XCD blocks get contiguous ROI ranges
  int j = blockIdx.x;
  int q = nb >> 3, rr = nb & 7;
  int xc = j & 7, loc = j >> 3;
  int blk = (xc < rr ? xc * (q + 1) : rr * (q + 1) + (xc - rr) * q) + loc;

  int sub = threadIdx.x & 31;           // channel chunk: ch = sub*8
  int bl  = threadIdx.x >> 5;           // local bin 0..7
  int w = blk * 8 + bl;
  if (w >= T) return;
  int bin = w % NBIN;
  int n   = w / NBIN;
  int ph  = bin / POOL, pw = bin % POOL;

  const float* r = rois + (size_t)n * 5;
  int   bidx = (int)r[0];
  float sx = fmaf(r[1], SP_SCALE, -0.5f);
  float sy = fmaf(r[2], SP_SCALE, -0.5f);
  float bw = (fmaf(r[3], SP_SCALE, -0.5f) - sx) * (1.0f / POOL);
  float bh = (fmaf(r[4], SP_SCALE, -0.5f) - sy) * (1.0f / POOL);

  int   rows[4]; float wy[4];
#pragma unroll
  for (int i = 0; i < 2; ++i) {
    float y = sy + ((float)ph + 0.25f + 0.5f * (float)i) * bh;
    bool v = (y > -1.0f) && (y < (float)Hc);
    float y0 = fmaxf(y, 0.0f);
    int lo = (int)y0;
    int hi;
    if (lo >= Hc - 1) { lo = Hc - 1; hi = Hc - 1; y0 = (float)lo; }
    else              { hi = lo + 1; }
    float f = y0 - (float)lo;
    rows[i * 2]     = lo; rows[i * 2 + 1] = hi;
    wy[i * 2]       = v ? (1.0f - f) * 0.25f : 0.0f;   // fold 1/(SR*SR)
    wy[i * 2 + 1]   = v ? f * 0.25f : 0.0f;
  }
  int   cols[4]; float wx[4];
#pragma unroll
  for (int i = 0; i < 2; ++i) {
    float x = sx + ((float)pw + 0.25f + 0.5f * (float)i) * bw;
    bool v = (x > -1.0f) && (x < (float)Wc);
    float x0 = fmaxf(x, 0.0f);
    int lo = (int)x0;
    int hi;
    if (lo >= Wc - 1) { lo = Wc - 1; hi = Wc - 1; x0 = (float)lo; }
    else              { hi = lo + 1; }
    float f = x0 - (float)lo;
    cols[i * 2]     = lo; cols[i * 2 + 1] = hi;
    wx[i * 2]       = v ? (1.0f - f) : 0.0f;
    wx[i * 2 + 1]   = v ? f : 0.0f;
  }

  const __half* fp = ft + (size_t)bidx * HWc * Cc + sub * 8;
  float a0 = 0.f, a1 = 0.f, a2 = 0.f, a3 = 0.f;
  float a4 = 0.f, a5 = 0.f, a6 = 0.f, a7 = 0.f;
#pragma unroll
  for (int rI = 0; rI < 4; ++rI) {
    const __half* rp = fp + (size_t)rows[rI] * (Wc * Cc);
#pragma unroll
    for (int cI = 0; cI < 4; ++cI) {
      union { uint4 u; __half2 h2[4]; } v;
      v.u = *(const uint4*)(rp + (size_t)cols[cI] * Cc);
      float wk = wy[rI] * wx[cI];
      float2 f0 = __half22float2(v.h2[0]);
      float2 f1 = __half22float2(v.h2[1]);
      float2 f2 = __half22float2(v.h2[2]);
      float2 f3 = __half22float2(v.h2[3]);
      a0 = fmaf(wk, f0.x, a0); a1 = fmaf(wk, f0.y, a1);
      a2 = fmaf(wk, f1.x, a2); a3 = fmaf(wk, f1.y, a3);
      a4 = fmaf(wk, f2.x, a4); a5 = fmaf(wk, f2.y, a5);
      a6 = fmaf(wk, f3.x, a6); a7 = fmaf(wk, f3.y, a7);
    }
  }

  // out is write-once, never re-read by us: nontemporal keeps feat+ft L3-resident
  float* op = out + ((size_t)n * Cc + (size_t)sub * 8) * NBIN + bin;
  __builtin_nontemporal_store(a0, op);
  __builtin_nontemporal_store(a1, op + NBIN);
  __builtin_nontemporal_store(a2, op + 2 * NBIN);
  __builtin_nontemporal_store(a3, op + 3 * NBIN);
  __builtin_nontemporal_store(a4, op + 4 * NBIN);
  __builtin_nontemporal_store(a5, op + 5 * NBIN);
  __builtin_nontemporal_store(a6, op + 6 * NBIN);
  __builtin_nontemporal_store(a7, op + 7 * NBIN);
}

// ---------------- Fallback if workspace too small ----------------
__global__ __launch_bounds__(256) void roi_align_fallback(
    const float* __restrict__ feat, const float* __restrict__ rois,
    float* __restrict__ out, int N) {
  long long idx = (long long)blockIdx.x * blockDim.x + threadIdx.x;
  long long total = (long long)N * Cc * NBIN;
  if (idx >= total) return;
  int pw = (int)(idx % POOL);
  int ph = (int)((idx / POOL) % POOL);
  int c  = (int)((idx / NBIN) % Cc);
  int n  = (int)(idx / ((long long)NBIN * Cc));
  const float* r = rois + (size_t)n * 5;
  int   b  = (int)r[0];
  float sx = fmaf(r[1], SP_SCALE, -0.5f);
  float sy = fmaf(r[2], SP_SCALE, -0.5f);
  float bw = (fmaf(r[3], SP_SCALE, -0.5f) - sx) * (1.0f / POOL);
  float bh = (fmaf(r[4], SP_SCALE, -0.5f) - sy) * (1.0f / POOL);
  const float* fp = feat + ((size_t)b * Cc + c) * (size_t)HWc;
  float acc = 0.0f;
#pragma unroll
  for (int iy = 0; iy < 2; ++iy) {
    float y = sy + ((float)ph + 0.25f + 0.5f * iy) * bh;
    bool vy = (y > -1.0f) && (y < (float)Hc);
    float y0 = fmaxf(y, 0.0f);
    int ylo = (int)y0, yhi;
    if (ylo >= Hc - 1) { ylo = Hc - 1; yhi = Hc - 1; y0 = (float)ylo; }
    else               { yhi = ylo + 1; }
    float ly = y0 - (float)ylo;
#pragma unroll
    for (int ix = 0; ix < 2; ++ix) {
      float x = sx + ((float)pw + 0.25f + 0.5f * ix) * bw;
      bool vx = (x > -1.0f) && (x < (float)Wc);
      float x0 = fmaxf(x, 0.0f);
      int xlo = (int)x0, xhi;
      if (xlo >= Wc - 1) { xlo = Wc - 1; xhi = Wc - 1; x0 = (float)xlo; }
      else               { xhi = xlo + 1; }
      float lx = x0 - (float)xlo;
      if (vy && vx) {
        float v00 = fp[(size_t)ylo * Wc + xlo];
        float v01 = fp[(size_t)ylo * Wc + xhi];
        float v10 = fp[(size_t)yhi * Wc + xlo];
        float v11 = fp[(size_t)yhi * Wc + xhi];
        acc += v00 * (1.0f - ly) * (1.0f - lx) + v01 * (1.0f - ly) * lx
             + v10 * ly * (1.0f - lx) + v11 * ly * lx;
      }
    }
  }
  out[idx] = acc * 0.25f;
}

extern "C" void kernel_launch(void* const* d_in, const int* in_sizes, int n_in,
                              void* d_out, int out_size, void* d_ws, size_t ws_size,
                              hipStream_t stream) {
  const float* feat = (const float*)d_in[0];
  const float* rois = (const float*)d_in[1];
  float* out = (float*)d_out;
  const int N = in_sizes[1] / 5;
  (void)n_in; (void)out_size;

  size_t need = (size_t)2 * Cc * HWc * sizeof(__half);  // 68.8 MB NHWC fp16 copy
  if (ws_size >= need) {
    __half* ft = (__half*)d_ws;
    dim3 tb(8, 32);
    dim3 tg(HWc / 32, Cc / 32, 2);
    transpose_f16_kernel<<<tg, tb, 0, stream>>>(feat, ft);
    int T = N * NBIN;
    int nb = (T + 7) / 8;
    gather_kernel<<<nb, 256, 0, stream>>>(ft, rois, out, N);
  } else {
    long long total = (long long)N * Cc * NBIN;
    roi_align_fallback<<<(int)((total + 255) / 256), 256, 0, stream>>>(feat, rois, out, N);
  }
}

// Round 7
// 90.499 us; speedup vs baseline: 3.4407x; 3.4407x over previous
//
#include <hip/hip_runtime.h>
#include <hip/hip_fp16.h>

#define POOL 7
#define NBIN 49
#define SP_SCALE 0.25f

constexpr int Cc = 256, Hc = 200, Wc = 336;
constexpr int HWc = Hc * Wc;          // 67200

// ---------------- Kernel 1: NCHW fp32 -> NHWC fp16 transpose ----------------
__global__ __launch_bounds__(256) void transpose_f16_kernel(
    const float* __restrict__ in, __half* __restrict__ outp) {
  __shared__ float tile[32][33];
  int b  = blockIdx.z;
  int p0 = blockIdx.x * 32;   // spatial
  int c0 = blockIdx.y * 32;   // channel
  const float* src = in   + (size_t)b * Cc * HWc;
  __half*      dst = outp + (size_t)b * Cc * HWc;
  int tx = threadIdx.x;   // 0..7
  int ty = threadIdx.y;   // 0..31

  float4 v = *(const float4*)(src + (size_t)(c0 + ty) * HWc + p0 + tx * 4);
  tile[ty][tx * 4 + 0] = v.x;
  tile[ty][tx * 4 + 1] = v.y;
  tile[ty][tx * 4 + 2] = v.z;
  tile[ty][tx * 4 + 3] = v.w;
  __syncthreads();
  union { __half h[4]; uint2 u; } o;
  o.h[0] = __float2half(tile[tx * 4 + 0][ty]);
  o.h[1] = __float2half(tile[tx * 4 + 1][ty]);
  o.h[2] = __float2half(tile[tx * 4 + 2][ty]);
  o.h[3] = __float2half(tile[tx * 4 + 3][ty]);
  *(uint2*)(dst + (size_t)(p0 + ty) * Cc + c0 + tx * 4) = o.u;
}

// ---------------- Kernel 2: gather. 8 bins/block, thread = 8 channels ----
// Load-all-then-math: 16 independent uint4 loads in flight per thread.
__global__ __launch_bounds__(256, 4) void gather_kernel(
    const __half* __restrict__ ft, const float* __restrict__ rois,
    float* __restrict__ out, int N) {
  int T  = N * NBIN;
  int nb = (T + 7) >> 3;                // 8 bins per 256-thread block
  // XCD-bijective swizzle: same-XCD blocks get contiguous ROI ranges
  int j = blockIdx.x;
  int q = nb >> 3, rr = nb & 7;
  int xc = j & 7, loc = j >> 3;
  int blk = (xc < rr ? xc * (q + 1) : rr * (q + 1) + (xc - rr) * q) + loc;

  int sub = threadIdx.x & 31;           // channel chunk: ch = sub*8
  int bl  = threadIdx.x >> 5;           // local bin 0..7
  int w = blk * 8 + bl;
  if (w >= T) return;
  int bin = w % NBIN;
  int n   = w / NBIN;
  int ph  = bin / POOL, pw = bin % POOL;

  const float* r = rois + (size_t)n * 5;
  int   bidx = (int)r[0];
  float sx = fmaf(r[1], SP_SCALE, -0.5f);
  float sy = fmaf(r[2], SP_SCALE, -0.5f);
  float bw = (fmaf(r[3], SP_SCALE, -0.5f) - sx) * (1.0f / POOL);
  float bh = (fmaf(r[4], SP_SCALE, -0.5f) - sy) * (1.0f / POOL);

  int   rows[4]; float wy[4];
#pragma unroll
  for (int i = 0; i < 2; ++i) {
    float y = sy + ((float)ph + 0.25f + 0.5f * (float)i) * bh;
    bool v = (y > -1.0f) && (y < (float)Hc);
    float y0 = fmaxf(y, 0.0f);
    int lo = (int)y0;
    int hi;
    if (lo >= Hc - 1) { lo = Hc - 1; hi = Hc - 1; y0 = (float)lo; }
    else              { hi = lo + 1; }
    float f = y0 - (float)lo;
    rows[i * 2]     = lo; rows[i * 2 + 1] = hi;
    wy[i * 2]       = v ? (1.0f - f) * 0.25f : 0.0f;   // fold 1/(SR*SR)
    wy[i * 2 + 1]   = v ? f * 0.25f : 0.0f;
  }
  int   cols[4]; float wx[4];
#pragma unroll
  for (int i = 0; i < 2; ++i) {
    float x = sx + ((float)pw + 0.25f + 0.5f * (float)i) * bw;
    bool v = (x > -1.0f) && (x < (float)Wc);
    float x0 = fmaxf(x, 0.0f);
    int lo = (int)x0;
    int hi;
    if (lo >= Wc - 1) { lo = Wc - 1; hi = Wc - 1; x0 = (float)lo; }
    else              { hi = lo + 1; }
    float f = x0 - (float)lo;
    cols[i * 2]     = lo; cols[i * 2 + 1] = hi;
    wx[i * 2]       = v ? (1.0f - f) : 0.0f;
    wx[i * 2 + 1]   = v ? f : 0.0f;
  }

  const __half* fp = ft + (size_t)bidx * HWc * Cc + sub * 8;

  // ---- phase 1: issue all 16 corner loads into independent registers
  uint4 v[16];
#pragma unroll
  for (int rI = 0; rI < 4; ++rI) {
    const __half* rp = fp + (size_t)rows[rI] * (Wc * Cc);
#pragma unroll
    for (int cI = 0; cI < 4; ++cI)
      v[rI * 4 + cI] = *(const uint4*)(rp + (size_t)cols[cI] * Cc);
  }

  // ---- phase 2: weighted accumulate
  float a0 = 0.f, a1 = 0.f, a2 = 0.f, a3 = 0.f;
  float a4 = 0.f, a5 = 0.f, a6 = 0.f, a7 = 0.f;
#pragma unroll
  for (int k = 0; k < 16; ++k) {
    float wk = wy[k >> 2] * wx[k & 3];
    union { uint4 u; __half2 h2[4]; } t;
    t.u = v[k];
    float2 f0 = __half22float2(t.h2[0]);
    float2 f1 = __half22float2(t.h2[1]);
    float2 f2 = __half22float2(t.h2[2]);
    float2 f3 = __half22float2(t.h2[3]);
    a0 = fmaf(wk, f0.x, a0); a1 = fmaf(wk, f0.y, a1);
    a2 = fmaf(wk, f1.x, a2); a3 = fmaf(wk, f1.y, a3);
    a4 = fmaf(wk, f2.x, a4); a5 = fmaf(wk, f2.y, a5);
    a6 = fmaf(wk, f3.x, a6); a7 = fmaf(wk, f3.y, a7);
  }

  float* op = out + ((size_t)n * Cc + (size_t)sub * 8) * NBIN + bin;
  op[0]        = a0;
  op[NBIN]     = a1;
  op[2 * NBIN] = a2;
  op[3 * NBIN] = a3;
  op[4 * NBIN] = a4;
  op[5 * NBIN] = a5;
  op[6 * NBIN] = a6;
  op[7 * NBIN] = a7;
}

// ---------------- Fallback if workspace too small ----------------
__global__ __launch_bounds__(256) void roi_align_fallback(
    const float* __restrict__ feat, const float* __restrict__ rois,
    float* __restrict__ out, int N) {
  long long idx = (long long)blockIdx.x * blockDim.x + threadIdx.x;
  long long total = (long long)N * Cc * NBIN;
  if (idx >= total) return;
  int pw = (int)(idx % POOL);
  int ph = (int)((idx / POOL) % POOL);
  int c  = (int)((idx / NBIN) % Cc);
  int n  = (int)(idx / ((long long)NBIN * Cc));
  const float* r = rois + (size_t)n * 5;
  int   b  = (int)r[0];
  float sx = fmaf(r[1], SP_SCALE, -0.5f);
  float sy = fmaf(r[2], SP_SCALE, -0.5f);
  float bw = (fmaf(r[3], SP_SCALE, -0.5f) - sx) * (1.0f / POOL);
  float bh = (fmaf(r[4], SP_SCALE, -0.5f) - sy) * (1.0f / POOL);
  const float* fp = feat + ((size_t)b * Cc + c) * (size_t)HWc;
  float acc = 0.0f;
#pragma unroll
  for (int iy = 0; iy < 2; ++iy) {
    float y = sy + ((float)ph + 0.25f + 0.5f * iy) * bh;
    bool vy = (y > -1.0f) && (y < (float)Hc);
    float y0 = fmaxf(y, 0.0f);
    int ylo = (int)y0, yhi;
    if (ylo >= Hc - 1) { ylo = Hc - 1; yhi = Hc - 1; y0 = (float)ylo; }
    else               { yhi = ylo + 1; }
    float ly = y0 - (float)ylo;
#pragma unroll
    for (int ix = 0; ix < 2; ++ix) {
      float x = sx + ((float)pw + 0.25f + 0.5f * ix) * bw;
      bool vx = (x > -1.0f) && (x < (float)Wc);
      float x0 = fmaxf(x, 0.0f);
      int xlo = (int)x0, xhi;
      if (xlo >= Wc - 1) { xlo = Wc - 1; xhi = Wc - 1; x0 = (float)xlo; }
      else               { xhi = xlo + 1; }
      float lx = x0 - (float)xlo;
      if (vy && vx) {
        float v00 = fp[(size_t)ylo * Wc + xlo];
        float v01 = fp[(size_t)ylo * Wc + xhi];
        float v10 = fp[(size_t)yhi * Wc + xlo];
        float v11 = fp[(size_t)yhi * Wc + xhi];
        acc += v00 * (1.0f - ly) * (1.0f - lx) + v01 * (1.0f - ly) * lx
             + v10 * ly * (1.0f - lx) + v11 * ly * lx;
      }
    }
  }
  out[idx] = acc * 0.25f;
}

extern "C" void kernel_launch(void* const* d_in, const int* in_sizes, int n_in,
                              void* d_out, int out_size, void* d_ws, size_t ws_size,
                              hipStream_t stream) {
  const float* feat = (const float*)d_in[0];
  const float* rois = (const float*)d_in[1];
  float* out = (float*)d_out;
  const int N = in_sizes[1] / 5;
  (void)n_in; (void)out_size;

  size_t need = (size_t)2 * Cc * HWc * sizeof(__half);  // 68.8 MB NHWC fp16 copy
  if (ws_size >= need) {
    __half* ft = (__half*)d_ws;
    dim3 tb(8, 32);
    dim3 tg(HWc / 32, Cc / 32, 2);
    transpose_f16_kernel<<<tg, tb, 0, stream>>>(feat, ft);
    int T = N * NBIN;
    int nb = (T + 7) / 8;
    gather_kernel<<<nb, 256, 0, stream>>>(ft, rois, out, N);
  } else {
    long long total = (long long)N * Cc * NBIN;
    roi_align_fallback<<<(int)((total + 255) / 256), 256, 0, stream>>>(feat, rois, out, N);
  }
}